// Round 1
// baseline (184.762 us; speedup 1.0000x reference)
//
#include <hip/hip_runtime.h>
#include <hip/hip_bf16.h>

typedef short bf16x8 __attribute__((ext_vector_type(8)));
typedef float f32x4 __attribute__((ext_vector_type(4)));

#define T_DIM 2048
#define D_DIM 64
#define WIN 128
#define QBLK 64
#define KWMAX 320
#define NKT_MAX 20
#define NS_MAX 10
#define NEGBIG -1e30f

__device__ __forceinline__ short f2b(float x) {
  __hip_bfloat16 h = __float2bfloat16(x);
  return *reinterpret_cast<short*>(&h);
}
// swizzled byte address inside a row-major LDS tile, 128B rows (Q, K)
__device__ __forceinline__ int swzQ(int row, int b) { return row * 128 + (b ^ ((row & 7) << 4)); }
// swizzled byte address inside a row-major LDS tile, 640B rows (Vt, P)
__device__ __forceinline__ int swzP(int row, int b) { return row * 640 + (b ^ ((row & 7) << 4)); }

__global__ __launch_bounds__(256, 1) void lsa_fused(
    const float* __restrict__ Qg, const float* __restrict__ Kg,
    const float* __restrict__ Vg, float* __restrict__ Og,
    float* __restrict__ Ag) {
  const int tid = threadIdx.x;
  const int q0 = blockIdx.x * QBLK;
  const int bh = blockIdx.y;
  int ks0 = q0 - WIN; if (ks0 < 0) ks0 = 0;
  int ke0 = q0 + QBLK + WIN; if (ke0 > T_DIM) ke0 = T_DIM;
  const int kstart = ks0;
  const int kend = ke0;
  const int KW = kend - kstart;   // 192 / 256 / 320, always multiple of 32
  const int nkt = KW >> 4;        // 16-wide k tiles
  const int ns = KW >> 5;         // 32-wide k slices

  const float* qptr = Qg + (size_t)bh * (T_DIM * D_DIM);
  const float* kptr = Kg + (size_t)bh * (T_DIM * D_DIM);
  const float* vptr = Vg + (size_t)bh * (T_DIM * D_DIM);
  float* optr = Og + (size_t)bh * (T_DIM * D_DIM);
  float* aptr = Ag + (size_t)bh * ((size_t)T_DIM * T_DIM);

  // LDS: Q 8KB + K 40KB + Vt 40KB + P 40KB = 128KB
  __shared__ __align__(16) char Qb[QBLK * 128];
  __shared__ __align__(16) char Kb[KWMAX * 128];
  __shared__ __align__(16) char Vb[D_DIM * 640];
  __shared__ __align__(16) char Pb[QBLK * 640];

  // ---- stage Q tile: 64 rows x 64 f32 -> bf16, swizzled 128B rows ----
  for (int idx = tid; idx < QBLK * 16; idx += 256) {
    const int r = idx >> 4, c4 = idx & 15;
    f32x4 f = *(const f32x4*)(qptr + (size_t)(q0 + r) * D_DIM + c4 * 4);
    short4 s4;
    s4.x = f2b(f[0]); s4.y = f2b(f[1]); s4.z = f2b(f[2]); s4.w = f2b(f[3]);
    *(short4*)(Qb + swzQ(r, c4 * 8)) = s4;
  }
  // ---- stage K window: KW rows x 64 f32 -> bf16, swizzled ----
  for (int idx = tid; idx < KW * 16; idx += 256) {
    const int r = idx >> 4, c4 = idx & 15;
    f32x4 f = *(const f32x4*)(kptr + (size_t)(kstart + r) * D_DIM + c4 * 4);
    short4 s4;
    s4.x = f2b(f[0]); s4.y = f2b(f[1]); s4.z = f2b(f[2]); s4.w = f2b(f[3]);
    *(short4*)(Kb + swzQ(r, c4 * 8)) = s4;
  }
  // ---- stage V transposed: Vt[d][k] bf16, 640B rows, swizzled ----
  for (int idx = tid; idx < KW * 16; idx += 256) {
    const int r = idx >> 4, c4 = idx & 15;
    f32x4 f = *(const f32x4*)(vptr + (size_t)(kstart + r) * D_DIM + c4 * 4);
    const int d0 = c4 * 4;
    *(short*)(Vb + swzP(d0 + 0, r * 2)) = f2b(f[0]);
    *(short*)(Vb + swzP(d0 + 1, r * 2)) = f2b(f[1]);
    *(short*)(Vb + swzP(d0 + 2, r * 2)) = f2b(f[2]);
    *(short*)(Vb + swzP(d0 + 3, r * 2)) = f2b(f[3]);
  }

  // ---- zero-fill out-of-band attn columns (stores drain under compute) ----
  {
    const f32x4 z = {0.f, 0.f, 0.f, 0.f};
    float* arow = aptr + (size_t)q0 * T_DIM;
    for (int r = 0; r < QBLK; ++r, arow += T_DIM) {
      for (int c = tid * 4; c < kstart; c += 1024) *(f32x4*)(arow + c) = z;
      for (int c = kend + tid * 4; c < T_DIM; c += 1024) *(f32x4*)(arow + c) = z;
    }
  }
  __syncthreads();

  const int lane = tid & 63;
  const int w = tid >> 6;       // wave id -> q sub-tile
  const int c = lane & 15;      // col within 16x16 tile
  const int hi = lane >> 4;     // 0..3

  // A-frags (Q rows of this wave's tile), d-slices 0..31 and 32..63
  bf16x8 a0 = *(const bf16x8*)(Qb + swzQ(w * 16 + c, 16 * hi));
  bf16x8 a1 = *(const bf16x8*)(Qb + swzQ(w * 16 + c, 64 + 16 * hi));

  // ---- S = Q K^T over the window ----
  f32x4 acc[NKT_MAX];
#pragma unroll
  for (int kt = 0; kt < NKT_MAX; ++kt) {
    acc[kt] = (f32x4){0.f, 0.f, 0.f, 0.f};
    if (kt < nkt) {
      bf16x8 b0 = *(const bf16x8*)(Kb + swzQ(kt * 16 + c, 16 * hi));
      bf16x8 b1 = *(const bf16x8*)(Kb + swzQ(kt * 16 + c, 64 + 16 * hi));
      acc[kt] = __builtin_amdgcn_mfma_f32_16x16x32_bf16(a0, b0, acc[kt], 0, 0, 0);
      acc[kt] = __builtin_amdgcn_mfma_f32_16x16x32_bf16(a1, b1, acc[kt], 0, 0, 0);
    }
  }

  // ---- masked softmax (fp32), write attn band + P bf16 to LDS ----
  const int kgc = kstart + c;
#pragma unroll
  for (int j = 0; j < 4; ++j) {
    const int qrow = q0 + w * 16 + 4 * hi + j;
    float m = NEGBIG;
#pragma unroll
    for (int kt = 0; kt < NKT_MAX; ++kt)
      if (kt < nkt) {
        const int kcol = kgc + kt * 16;
        float s = acc[kt][j] * 0.125f;           // 1/sqrt(64)
        int dist = qrow - kcol; dist = dist < 0 ? -dist : dist;
        s = (dist <= WIN) ? s : NEGBIG;
        acc[kt][j] = s;
        m = fmaxf(m, s);
      }
    m = fmaxf(m, __shfl_xor(m, 1));
    m = fmaxf(m, __shfl_xor(m, 2));
    m = fmaxf(m, __shfl_xor(m, 4));
    m = fmaxf(m, __shfl_xor(m, 8));
    float sum = 0.f;
#pragma unroll
    for (int kt = 0; kt < NKT_MAX; ++kt)
      if (kt < nkt) {
        float p = __expf(acc[kt][j] - m);
        acc[kt][j] = p;
        sum += p;
      }
    sum += __shfl_xor(sum, 1);
    sum += __shfl_xor(sum, 2);
    sum += __shfl_xor(sum, 4);
    sum += __shfl_xor(sum, 8);
    const float inv = 1.f / sum;
    float* arow = aptr + (size_t)qrow * T_DIM;
#pragma unroll
    for (int kt = 0; kt < NKT_MAX; ++kt)
      if (kt < nkt) {
        float p = acc[kt][j] * inv;
        arow[kgc + kt * 16] = p;
        *(short*)(Pb + swzP(w * 16 + 4 * hi + j, (kt * 16 + c) * 2)) = f2b(p);
      }
  }
  // no barrier needed: each wave reads back only the P rows it wrote; Vt was
  // staged before the __syncthreads above.

  // ---- O = P V ----
  f32x4 ov[4];
#pragma unroll
  for (int dt = 0; dt < 4; ++dt) ov[dt] = (f32x4){0.f, 0.f, 0.f, 0.f};
#pragma unroll
  for (int s = 0; s < NS_MAX; ++s)
    if (s < ns) {
      bf16x8 pa = *(const bf16x8*)(Pb + swzP(w * 16 + c, 64 * s + 16 * hi));
#pragma unroll
      for (int dt = 0; dt < 4; ++dt) {
        bf16x8 vb = *(const bf16x8*)(Vb + swzP(dt * 16 + c, 64 * s + 16 * hi));
        ov[dt] = __builtin_amdgcn_mfma_f32_16x16x32_bf16(pa, vb, ov[dt], 0, 0, 0);
      }
    }
#pragma unroll
  for (int dt = 0; dt < 4; ++dt) {
#pragma unroll
    for (int j = 0; j < 4; ++j) {
      optr[(size_t)(q0 + w * 16 + 4 * hi + j) * D_DIM + dt * 16 + c] = ov[dt][j];
    }
  }
}

extern "C" void kernel_launch(void* const* d_in, const int* in_sizes, int n_in,
                              void* d_out, int out_size, void* d_ws, size_t ws_size,
                              hipStream_t stream) {
  const float* q = (const float*)d_in[0];
  const float* k = (const float*)d_in[1];
  const float* v = (const float*)d_in[2];
  float* out = (float*)d_out;
  float* attn = out + (size_t)2 * 16 * T_DIM * D_DIM;  // output first, then attn
  dim3 grid(T_DIM / QBLK, 2 * 16);
  lsa_fused<<<grid, 256, 0, stream>>>(q, k, v, out, attn);
}